// Round 11
// baseline (1258.925 us; speedup 1.0000x reference)
//
#include <hip/hip_runtime.h>
#include <hip/hip_bf16.h>
#include <stdint.h>

// Problem: S=512, N=64, E=256, NH=8, HD=32, LH=512.
// Pipeline: convert -> qkv -> attn -> outproj -> gates GEMM -> persistent LSTM -> final proj.
// R17 = R16 (slot-major h-ring: the -42% k_lstm win) + three low-risk cuts:
//  - k_lstm poll: pair-wise replica reads (replicas are content-equivalent — written
//    simultaneously; replication exists only for consumer-L1 freshness). Reading r and
//    r+1 in parallel and accepting (v0|v1) halves serial L2 RTTs in the miss path.
//    Schedule/ring/flags otherwise VERBATIM R16.
//  - k_convert also pre-converts in_proj_w + mha_out_w to bf16 (+256 blocks);
//    k_qkv/k_outproj stage B tiles from bf16 (half traffic, no convert ALU,
//    bit-identical Bs content — same f2bf).
// Kept: m97-staged k_gates, 1024-block k_attn with vectorized softmax + P-writeback.

typedef __attribute__((ext_vector_type(8))) short bf16x8;
typedef __attribute__((ext_vector_type(4))) float f32x4;

__device__ __forceinline__ unsigned short f2bf(float f){
  unsigned u = __float_as_uint(f);
  u += 0x7FFFu + ((u >> 16) & 1u);          // RNE
  return (unsigned short)(u >> 16);
}
__device__ __forceinline__ float b2f(unsigned short h){
  return __uint_as_float(((unsigned)h) << 16);
}
__device__ __forceinline__ ushort4 f4tobf(float4 f){
  ushort4 o; o.x=f2bf(f.x); o.y=f2bf(f.y); o.z=f2bf(f.z); o.w=f2bf(f.w); return o;
}
// async global->LDS, 16B per lane: per-lane global src, wave-uniform LDS base (+lane*16).
__device__ __forceinline__ void gload_lds16(const void* g, void* l){
  __builtin_amdgcn_global_load_lds((const __attribute__((address_space(1))) unsigned int*)g,
                                   (__attribute__((address_space(3))) unsigned int*)l, 16, 0, 0);
}

// ---------------- workspace layout (bytes) ----------------
// flagsIC:  [0x0,      0x4000)   8 groups x 32 slots, 64B stride (IC fallback flags)
// cnt:      [0x4000,   0x4020)   8 ints, per-XCD slot claim
// pooled:   [0x30000,  0x50000)  64x512 f32
// w_ih bf16:[0x50000,  0x250000)
// in_w bf16:[0x250000, 0x2B0000) 768x256
// mo_w bf16:[0x2B0000, 0x2D0000) 256x256
// flr:      [0x300000, 0x700000) replicated L2 flags: [st][r<8][g][slot] int, 4MB
// combined: [0x800000, 0x2800000) 32768x512 bf16; REUSED by k_lstm as h-ring:
//           ring[st][g][slot][batch][u16] = 8KB per (st,g); 64KB/step, 32MB total
// gates:    [0x3000000,0xB000000) layout [m][u][gate] = m*2048 + u*4 + gate (aliases q/k/v/ctx)
// q:0x3000000 k:0x4000000 v:0x5000000 ctx:0x6000000 (each 16MB bf16)
// total required ws: 0xB000000 = 184,549,376 B

// K0: w_ih, x, in_proj_w, mha_out_w  fp32 -> bf16
__global__ __launch_bounds__(256) void k_convert(const float* __restrict__ wih,
                                                 const float* __restrict__ x,
                                                 const float* __restrict__ inw,
                                                 const float* __restrict__ mow,
                                                 unsigned short* __restrict__ wih_bf,
                                                 unsigned short* __restrict__ comb,
                                                 unsigned short* __restrict__ inw_bf,
                                                 unsigned short* __restrict__ mow_bf){
  size_t i = ((size_t)blockIdx.x * 256 + threadIdx.x) * 4;
  if (i < 1048576){
    float4 f = *(const float4*)(wih + i);
    *(ushort4*)(wih_bf + i) = f4tobf(f);
  } else {
    size_t j = i - 1048576;
    if (j < 8388608){
      float4 f = *(const float4*)(x + j);
      size_t m = j >> 8, c = j & 255;
      *(ushort4*)(comb + m*512 + c) = f4tobf(f);
    } else {
      size_t p = j - 8388608;
      if (p < 196608){
        float4 f = *(const float4*)(inw + p);
        *(ushort4*)(inw_bf + p) = f4tobf(f);
      } else {
        size_t qq = p - 196608;
        if (qq < 65536){
          float4 f = *(const float4*)(mow + qq);
          *(ushort4*)(mow_bf + qq) = f4tobf(f);
        }
      }
    }
  }
}

// K1: qkv = x @ in_proj_w.T + b ; scale folded into q; writes q/k [n][h][s][d], v transposed [n][h][d][s]
__global__ __launch_bounds__(256) void k_qkv(const unsigned short* __restrict__ xb,
                                             const unsigned short* __restrict__ wbf,
                                             const float* __restrict__ bias,
                                             unsigned short* __restrict__ q,
                                             unsigned short* __restrict__ kk,
                                             unsigned short* __restrict__ v){
  const int nt = blockIdx.x;    // 0..11
  const int mt = blockIdx.y;    // 0..511  (= s, since M-row = s*64+n)
  __shared__ unsigned short Bs[64][264];
  const int t = threadIdx.x;
  { // stage B tile (bf16, pre-converted)
    int row = t >> 2, c0 = (t & 3) * 64;
    const unsigned short* src = wbf + (size_t)(nt*64 + row)*256 + c0;
    #pragma unroll
    for (int i = 0; i < 64; i += 8)
      *(bf16x8*)&Bs[row][c0 + i] = *(const bf16x8*)(src + i);
  }
  __syncthreads();
  const int w4 = t >> 6, l = t & 63, lr = l & 15, lc = l >> 4;
  f32x4 acc[4];
  #pragma unroll
  for (int i = 0; i < 4; ++i) acc[i] = (f32x4){0.f,0.f,0.f,0.f};
  const size_t arow = (size_t)(mt*64 + w4*16 + lr) * 512;  // A from combined (bf16 x)
  #pragma unroll
  for (int kt = 0; kt < 8; ++kt){
    bf16x8 a = *(const bf16x8*)(xb + arow + kt*32 + lc*8);
    #pragma unroll
    for (int n4 = 0; n4 < 4; ++n4){
      bf16x8 b = *(const bf16x8*)&Bs[n4*16 + lr][kt*32 + lc*8];
      acc[n4] = __builtin_amdgcn_mfma_f32_16x16x32_bf16(a, b, acc[n4], 0, 0, 0);
    }
  }
  const int s = mt;
  #pragma unroll
  for (int n4 = 0; n4 < 4; ++n4){
    int ncol = nt*64 + n4*16 + lr;
    float bv = bias[ncol];
    int which = ncol >> 8, rem = ncol & 255, hh = rem >> 5, d = rem & 31;
    #pragma unroll
    for (int reg = 0; reg < 4; ++reg){
      int nb = w4*16 + lc*4 + reg;   // batch
      float val = acc[n4][reg] + bv;
      if (which == 0){
        val *= 0.17677669529663687f;  // 1/sqrt(32)
        q[((size_t)(nb*8 + hh)*512 + s)*32 + d] = f2bf(val);
      } else if (which == 1){
        kk[((size_t)(nb*8 + hh)*512 + s)*32 + d] = f2bf(val);
      } else {
        v[((size_t)(nb*8 + hh)*32 + d)*512 + s] = f2bf(val);
      }
    }
  }
}

// K2: attention; 2 blocks per (n,h), each does 8 Q-tiles -> 1024 blocks, 4/CU.
// Vectorized softmax; P written back into sc (bit-identical); PV reads P directly.
__global__ __launch_bounds__(256) void k_attn(const unsigned short* __restrict__ q,
                                              const unsigned short* __restrict__ k,
                                              const unsigned short* __restrict__ v,
                                              unsigned short* __restrict__ ctx){
  const int bid = blockIdx.x;
  const int nh = bid >> 1, qh = bid & 1;
  const int n = nh >> 3, h = nh & 7;
  __shared__ unsigned short sc[32][520];
  __shared__ float red[32][8];
  __shared__ float rowinv[32];
  const unsigned short* qb = q + (size_t)nh * 512 * 32;
  const unsigned short* kb = k + (size_t)nh * 512 * 32;
  const unsigned short* vb = v + (size_t)nh * 32 * 512;
  const int t = threadIdx.x, w4 = t >> 6, l = t & 63, lr = l & 15, lc = l >> 4;
  const int r = t >> 3, cc = t & 7;
  for (int qt = qh*8; qt < qh*8 + 8; ++qt){
    const int s0 = qt * 32;
    bf16x8 aq0 = *(const bf16x8*)(qb + (size_t)(s0 + lr)*32 + lc*8);
    bf16x8 aq1 = *(const bf16x8*)(qb + (size_t)(s0 + 16 + lr)*32 + lc*8);
    #pragma unroll
    for (int j = 0; j < 8; ++j){
      int ntl = w4*8 + j;
      bf16x8 bk = *(const bf16x8*)(kb + (size_t)(ntl*16 + lr)*32 + lc*8);
      f32x4 d0 = (f32x4){0.f,0.f,0.f,0.f}, d1 = (f32x4){0.f,0.f,0.f,0.f};
      d0 = __builtin_amdgcn_mfma_f32_16x16x32_bf16(aq0, bk, d0, 0, 0, 0);
      d1 = __builtin_amdgcn_mfma_f32_16x16x32_bf16(aq1, bk, d1, 0, 0, 0);
      #pragma unroll
      for (int reg = 0; reg < 4; ++reg){
        sc[lc*4 + reg][ntl*16 + lr]      = f2bf(d0[reg]);
        sc[16 + lc*4 + reg][ntl*16 + lr] = f2bf(d1[reg]);
      }
    }
    __syncthreads();
    float pm = -1e30f;
    #pragma unroll
    for (int i = 0; i < 8; ++i){
      bf16x8 vv = *(const bf16x8*)&sc[r][(i*8 + cc)*8];
      #pragma unroll
      for (int e = 0; e < 8; ++e) pm = fmaxf(pm, b2f((unsigned short)vv[e]));
    }
    red[r][cc] = pm;
    __syncthreads();
    float mfull = red[r][0];
    #pragma unroll
    for (int i = 1; i < 8; ++i) mfull = fmaxf(mfull, red[r][i]);
    __syncthreads();
    float sum = 0.f;
    #pragma unroll
    for (int i = 0; i < 8; ++i){
      bf16x8 vv = *(const bf16x8*)&sc[r][(i*8 + cc)*8];
      bf16x8 pv;
      #pragma unroll
      for (int e = 0; e < 8; ++e){
        float p = __expf(b2f((unsigned short)vv[e]) - mfull);
        sum += p;
        pv[e] = (short)f2bf(p);
      }
      *(bf16x8*)&sc[r][(i*8 + cc)*8] = pv;
    }
    red[r][cc] = sum;
    __syncthreads();
    float ss = 0.f;
    #pragma unroll
    for (int i = 0; i < 8; ++i) ss += red[r][i];
    rowinv[r] = 1.f / ss;
    __syncthreads();
    const int mt = w4 >> 1, ntd = w4 & 1;
    const int arow = mt*16 + lr;
    f32x4 o = (f32x4){0.f,0.f,0.f,0.f};
    for (int kt = 0; kt < 16; ++kt){
      bf16x8 ap = *(const bf16x8*)&sc[arow][kt*32 + lc*8];
      bf16x8 bv = *(const bf16x8*)(vb + (size_t)(ntd*16 + lr)*512 + kt*32 + lc*8);
      o = __builtin_amdgcn_mfma_f32_16x16x32_bf16(ap, bv, o, 0, 0, 0);
    }
    #pragma unroll
    for (int reg = 0; reg < 4; ++reg){
      int row = mt*16 + lc*4 + reg;
      int d = ntd*16 + lr;
      float val = o[reg] * rowinv[row];
      ctx[((size_t)(s0 + row)*64 + n)*256 + h*32 + d] = f2bf(val);
    }
    __syncthreads();
  }
}

// K3: attn_out = ctx @ mha_out_w.T + b -> combined[:, 256:512]
__global__ __launch_bounds__(256) void k_outproj(const unsigned short* __restrict__ ctx,
                                                 const unsigned short* __restrict__ wbf,
                                                 const float* __restrict__ bias,
                                                 unsigned short* __restrict__ comb){
  const int nt = blockIdx.x;   // 0..3
  const int mt = blockIdx.y;   // 0..511
  __shared__ unsigned short Bs[64][264];
  const int t = threadIdx.x;
  { // stage B tile (bf16, pre-converted)
    int row = t >> 2, c0 = (t & 3) * 64;
    const unsigned short* src = wbf + (size_t)(nt*64 + row)*256 + c0;
    #pragma unroll
    for (int i = 0; i < 64; i += 8)
      *(bf16x8*)&Bs[row][c0 + i] = *(const bf16x8*)(src + i);
  }
  __syncthreads();
  const int w4 = t >> 6, l = t & 63, lr = l & 15, lc = l >> 4;
  f32x4 acc[4];
  #pragma unroll
  for (int i = 0; i < 4; ++i) acc[i] = (f32x4){0.f,0.f,0.f,0.f};
  const size_t arow = (size_t)(mt*64 + w4*16 + lr) * 256;
  #pragma unroll
  for (int kt = 0; kt < 8; ++kt){
    bf16x8 a = *(const bf16x8*)(ctx + arow + kt*32 + lc*8);
    #pragma unroll
    for (int n4 = 0; n4 < 4; ++n4){
      bf16x8 b = *(const bf16x8*)&Bs[n4*16 + lr][kt*32 + lc*8];
      acc[n4] = __builtin_amdgcn_mfma_f32_16x16x32_bf16(a, b, acc[n4], 0, 0, 0);
    }
  }
  #pragma unroll
  for (int n4 = 0; n4 < 4; ++n4){
    int ncol = nt*64 + n4*16 + lr;
    float bv = bias[ncol];
    #pragma unroll
    for (int reg = 0; reg < 4; ++reg){
      int m = mt*64 + w4*16 + lc*4 + reg;
      comb[(size_t)m*512 + 256 + ncol] = f2bf(acc[n4][reg] + bv);
    }
  }
}

// K4: gates_x = combined @ w_ih.T + (b_ih + b_hh), 128x128 tiles, BK=64.
// m97-style staging: global_load_lds(16B) into linear [128][64] LDS; XOR chunk swizzle
// on GLOBAL source + LDS read. Output: gates[m][u][gate] = m*2048+u*4+gate.
__global__ __launch_bounds__(256) void k_gates(const unsigned short* __restrict__ A,
                                               const unsigned short* __restrict__ B,
                                               const float* __restrict__ bih,
                                               const float* __restrict__ bhh,
                                               unsigned short* __restrict__ gates){
  const int ntile = blockIdx.x;  // 0..15
  const int mtile = blockIdx.y;  // 0..255
  __shared__ unsigned short As[128][64], Bss[128][64];
  const int t = threadIdx.x, w4 = t >> 6, l = t & 63, lr = l & 15, lc = l >> 4;
  const int wm = w4 >> 1, wn = w4 & 1;
  f32x4 acc[4][4];
  #pragma unroll
  for (int i = 0; i < 4; ++i)
    #pragma unroll
    for (int j = 0; j < 4; ++j) acc[i][j] = (f32x4){0.f,0.f,0.f,0.f};
  const int ch = (l & 7) ^ (l >> 3);       // inverse-swizzled global chunk for this lane
  for (int kkk = 0; kkk < 8; ++kkk){
    #pragma unroll
    for (int c = 0; c < 4; ++c){
      const int row = w4*32 + c*8 + (l >> 3);
      gload_lds16(A + (size_t)(mtile*128 + row)*512 + kkk*64 + ch*8, &As [w4*32 + c*8][0]);
      gload_lds16(B + (size_t)(ntile*128 + row)*512 + kkk*64 + ch*8, &Bss[w4*32 + c*8][0]);
    }
    __syncthreads();   // compiler drains vmcnt before s_barrier -> LDS tiles complete
    #pragma unroll
    for (int kt = 0; kt < 2; ++kt){
      bf16x8 af[4], bfr[4];
      #pragma unroll
      for (int i = 0; i < 4; ++i)
        af[i]  = *(const bf16x8*)&As [wm*64 + i*16 + lr][(((kt*4 + lc) ^ (lr & 7)) * 8)];
      #pragma unroll
      for (int i = 0; i < 4; ++i)
        bfr[i] = *(const bf16x8*)&Bss[wn*64 + i*16 + lr][(((kt*4 + lc) ^ (lr & 7)) * 8)];
      #pragma unroll
      for (int i = 0; i < 4; ++i)
        #pragma unroll
        for (int j = 0; j < 4; ++j)
          acc[i][j] = __builtin_amdgcn_mfma_f32_16x16x32_bf16(af[i], bfr[j], acc[i][j], 0, 0, 0);
    }
    __syncthreads();
  }
  #pragma unroll
  for (int i = 0; i < 4; ++i){
    #pragma unroll
    for (int j = 0; j < 4; ++j){
      int ncol = ntile*128 + wn*64 + j*16 + lr;
      int gate = ncol >> 9, u = ncol & 511;
      float bsum = bih[ncol] + bhh[ncol];
      #pragma unroll
      for (int reg = 0; reg < 4; ++reg){
        int m = mtile*128 + wm*64 + i*16 + lc*4 + reg;
        gates[(size_t)m*2048 + u*4 + gate] = f2bf(acc[i][j][reg] + bsum);
      }
    }
  }
}

// K5: persistent LSTM, XCD-local — R16 schedule/ring verbatim; R17: pair-wise replica poll.
// ring[st][g] = [slot][batch][u16]: producer waves write ONE contiguous 128B line;
// consumer loads 16x b128. Handshake: replicated write-once L2 flags + IC fallback.
__global__ __launch_bounds__(256, 1) void k_lstm(const float* __restrict__ whh,
                                                 const unsigned short* __restrict__ gates,
                                                 unsigned short* __restrict__ ring,
                                                 float* __restrict__ pooled,
                                                 int* __restrict__ flagsIC,
                                                 int* __restrict__ flr,
                                                 int* __restrict__ cnt){
  __shared__ unsigned short Wl[64][512];   // 64KB: rows = gate*16+unit
  __shared__ f32x4 Dg[4*2*16];             // 2KB:  [gate][lc][unit]
  __shared__ float padlds[5120];           // 20KB pad -> 86KB total -> 1 WG/CU
  __shared__ int s_hdr[2];
  const int t = threadIdx.x, w4 = t >> 6, l = t & 63, lr = l & 15, lc = l >> 4;
  if ((int)blockIdx.x == -1) ((volatile float*)padlds)[0] = 1.f;  // keep padlds
  if (t == 0){
    unsigned xcc;
    asm volatile("s_getreg_b32 %0, hwreg(HW_REG_XCC_ID)" : "=s"(xcc));
    int g = (int)(xcc & 7);
    s_hdr[0] = g;
    s_hdr[1] = atomicAdd(&cnt[g], 1);      // device-scope claim
  }
  __syncthreads();
  const int g = s_hdr[0], slot = s_hdr[1];
  if (slot >= 32) return;                  // spare WG: free the CU immediately
  const int j0 = slot * 16;
  { // stage w_hh slice fp32->bf16, chunk swizzle phys = logical ^ (row&7)
    const int row = t >> 2;
    const int gate = row >> 4, u = row & 15;
    const float* src = whh + (size_t)(gate*512 + j0 + u) * 512;
    const int cbase = (t & 3) * 16;
    #pragma unroll
    for (int i = 0; i < 16; ++i){
      const int lch = cbase + i;
      float4 f0 = *(const float4*)(src + lch*8);
      float4 f1 = *(const float4*)(src + lch*8 + 4);
      const int pch = lch ^ (row & 7);
      *(ushort4*)&Wl[row][pch*8]     = f4tobf(f0);
      *(ushort4*)&Wl[row][pch*8 + 4] = f4tobf(f1);
    }
  }
  const int eb = t >> 4, eu = t & 15;      // elementwise ownership, t<128: (batch, unit)
  float cst = 0.f, pool = 0.f;
  unsigned long long gx = 0, nx = 0;
  if (t < 128)
    gx = *(const unsigned long long*)(gates + (size_t)(g*8 + eb)*2048 + (j0 + eu)*4);
  int* const myflagIC = &flagsIC[(g*32 + slot)*16];
  __syncthreads();
  for (int st = 0; st < 512; ++st){
    if (st > 0){
      if (t < 32){
        // pair-wise fresh-address poll: replicas are written simultaneously, so
        // accept (v0|v1) per slot — halves serial L2 RTTs in the miss path.
        bool need = true;
        #pragma unroll 1
        for (int r = 0; r < 8 && need; r += 2){
          int v0 = ((volatile const int*)flr)[((st*8 + r    )*8 + g)*32 + (t & 31)];
          int v1 = ((volatile const int*)flr)[((st*8 + r + 1)*8 + g)*32 + (t & 31)];
          need = (bool)__any((v0 | v1) == 0);
        }
        if (need){
          // pathological skew: proven IC atomic poll (bounded, correct-by-delay)
          int* fp = &flagsIC[(g*32 + (t & 31))*16];
          int t2 = 0;
          while (__hip_atomic_load(fp, __ATOMIC_RELAXED, __HIP_MEMORY_SCOPE_AGENT) < st
                 && ++t2 < 5000) { }
        }
      }
      __syncthreads();
    }
    // h(st) @ Wl^T : slot-major ring; element (b, u) at base + (u>>4)*128 + b*16 + (u&15).
    const unsigned short* ha = ring + (((size_t)st*8 + g) << 12)
                               + (lc >> 1)*128 + (lr & 7)*16 + (lc & 1)*8;
    bf16x8 areg[16];
    #pragma unroll
    for (int kt = 0; kt < 16; ++kt) areg[kt] = *(const bf16x8*)(ha + kt*256);
    if (st < 511 && t < 128)
      nx = *(const unsigned long long*)(gates + ((size_t)(st+1)*64 + g*8 + eb)*2048 + (j0 + eu)*4);
    f32x4 acc0 = (f32x4){0.f,0.f,0.f,0.f}, acc1 = (f32x4){0.f,0.f,0.f,0.f};
    #pragma unroll
    for (int kt = 0; kt < 16; kt += 2){
      bf16x8 b0 = *(const bf16x8*)&Wl[w4*16 + lr][(((kt  )*4 + lc) ^ (lr & 7)) * 8];
      bf16x8 b1 = *(const bf16x8*)&Wl[w4*16 + lr][(((kt+1)*4 + lc) ^ (lr & 7)) * 8];
      acc0 = __builtin_amdgcn_mfma_f32_16x16x32_bf16(areg[kt],   b0, acc0, 0, 0, 0);
      acc1 = __builtin_amdgcn_mfma_f32_16x16x32_bf16(areg[kt+1], b1, acc1, 0, 0, 0);
    }
    f32x4 acc = acc0 + acc1;
    if (lc < 2) Dg[(w4*2 + lc)*16 + lr] = acc;   // D: col=unit(lane&15), row=batch(lc*4+reg)
    __syncthreads();
    if (t < 128){
      union { unsigned long long q; unsigned short u[4]; } ga; ga.q = gx;
      const int dq = (eb >> 2)*16 + eu, dr = eb & 3;
      float gi = Dg[0*32 + dq][dr] + b2f(ga.u[0]);
      float gf = Dg[1*32 + dq][dr] + b2f(ga.u[1]);
      float gc = Dg[2*32 + dq][dr] + b2f(ga.u[2]);
      float go = Dg[3*32 + dq][dr] + b2f(ga.u[3]);
      float i_ = __builtin_amdgcn_rcpf(1.f + __expf(-gi));
      float f_ = __builtin_amdgcn_rcpf(1.f + __expf(-gf));
      float cg = fminf(fmaxf(gc, -20.f), 20.f);
      float e2 = __expf(2.f * cg);
      float g_ = 1.f - 2.f * __builtin_amdgcn_rcpf(e2 + 1.f);
      float o_ = __builtin_amdgcn_rcpf(1.f + __expf(-go));
      float cn = f_ * cst + i_ * g_;
      cst = cn;
      float ct = fminf(fmaxf(cn, -20.f), 20.f);
      float e2c = __expf(2.f * ct);
      float th = 1.f - 2.f * __builtin_amdgcn_rcpf(e2c + 1.f);
      float hh = o_ * th;
      pool += hh;
      if (st < 511)  // slot-major: lanes t<128 write offsets slot*128+t -> each wave
                     // one contiguous 128B line, write-through to this XCD's L2
        ring[(((size_t)(st+1)*8 + g) << 12) + slot*128 + t] = f2bf(hh);
      gx = nx;
    }
    __syncthreads();   // pre-barrier vmcnt(0) drains h stores to L2 [m97-measured semantics]
    if (st < 511){
      // h(st+1) in L2 now. Notify: 8 write-once L2 replicas (flag-in-L2 => h-in-L2,
      // same cache) + 1 IC flag for the fallback path.
      if (t < 8) flr[(((st+1)*8 + t)*8 + g)*32 + slot] = 1;
      if (t == 0) __hip_atomic_store(myflagIC, st + 1, __ATOMIC_RELAXED, __HIP_MEMORY_SCOPE_AGENT);
    }
  }
  if (t < 128)
    pooled[(size_t)(g*8 + eb)*512 + j0 + eu] = pool * (1.f / 512.f);
}

// K6: out = log_sigmoid(pooled @ proj_w.T + proj_b)
__global__ __launch_bounds__(256) void k_final(const float* __restrict__ pooled,
                                               const float* __restrict__ w,
                                               const float* __restrict__ bias,
                                               float* __restrict__ out){
  const int n = blockIdx.x;
  __shared__ float pr[512];
  const int t = threadIdx.x;
  pr[t]       = pooled[(size_t)n*512 + t];
  pr[t + 256] = pooled[(size_t)n*512 + t + 256];
  __syncthreads();
  const float* wr = w + (size_t)t * 512;
  float s = bias[t];
  for (int i = 0; i < 512; i += 4){
    float4 f = *(const float4*)(wr + i);
    s += f.x*pr[i] + f.y*pr[i+1] + f.z*pr[i+2] + f.w*pr[i+3];
  }
  float rres = fminf(s, 0.f) - log1pf(__expf(-fabsf(s)));
  out[(size_t)n*256 + t] = rres;
}

extern "C" void kernel_launch(void* const* d_in, const int* in_sizes, int n_in,
                              void* d_out, int out_size, void* d_ws, size_t ws_size,
                              hipStream_t stream){
  const float* x      = (const float*)d_in[0];
  const float* in_w   = (const float*)d_in[1];
  const float* in_b   = (const float*)d_in[2];
  const float* mo_w   = (const float*)d_in[3];
  const float* mo_b   = (const float*)d_in[4];
  const float* w_ih   = (const float*)d_in[5];
  const float* w_hh   = (const float*)d_in[6];
  const float* b_ih   = (const float*)d_in[7];
  const float* b_hh   = (const float*)d_in[8];
  const float* proj_w = (const float*)d_in[9];
  const float* proj_b = (const float*)d_in[10];
  uint8_t* ws = (uint8_t*)d_ws;
  int*            flagsIC = (int*)(ws + 0x0);
  int*            cnt     = (int*)(ws + 0x4000);
  float*          pooled  = (float*)(ws + 0x30000);
  unsigned short* wihbf   = (unsigned short*)(ws + 0x50000);
  unsigned short* inwbf   = (unsigned short*)(ws + 0x250000);
  unsigned short* mowbf   = (unsigned short*)(ws + 0x2B0000);
  int*            flr     = (int*)(ws + 0x300000);
  unsigned short* comb    = (unsigned short*)(ws + 0x800000);  // doubles as h-ring in k_lstm
  unsigned short* gates   = (unsigned short*)(ws + 0x3000000);
  unsigned short* qbuf    = (unsigned short*)(ws + 0x3000000); // aliases gates (dead before k_gates)
  unsigned short* kbuf    = (unsigned short*)(ws + 0x4000000);
  unsigned short* vbuf    = (unsigned short*)(ws + 0x5000000);
  unsigned short* ctx     = (unsigned short*)(ws + 0x6000000);

  hipMemsetAsync(ws + 0x300000, 0, 0x400000, stream);  // flr
  hipMemsetAsync(ws, 0, 0x4020, stream);               // flagsIC + cnt
  hipLaunchKernelGGL(k_convert, dim3(9472),    dim3(256), 0, stream, w_ih, x, in_w, mo_w,
                     wihbf, comb, inwbf, mowbf);
  hipLaunchKernelGGL(k_qkv,     dim3(12, 512), dim3(256), 0, stream, comb, inwbf, in_b, qbuf, kbuf, vbuf);
  hipLaunchKernelGGL(k_attn,    dim3(1024),    dim3(256), 0, stream, qbuf, kbuf, vbuf, ctx);
  hipLaunchKernelGGL(k_outproj, dim3(4, 512),  dim3(256), 0, stream, ctx, mowbf, mo_b, comb);
  hipLaunchKernelGGL(k_gates,   dim3(16, 256), dim3(256), 0, stream, comb, wihbf, b_ih, b_hh, gates);
  hipMemsetAsync(comb, 0, 0x10000, stream);  // h-ring slot 0 = h(-1) = zeros (comb dead now)
  hipLaunchKernelGGL(k_lstm,    dim3(512),     dim3(256), 0, stream, w_hh, gates, comb, pooled, flagsIC, flr, cnt);
  hipLaunchKernelGGL(k_final,   dim3(64),      dim3(256), 0, stream, pooled, proj_w, proj_b, (float*)d_out);
}

// Round 12
// 1125.165 us; speedup vs baseline: 1.1189x; 1.1189x over previous
//
#include <hip/hip_runtime.h>
#include <hip/hip_bf16.h>
#include <stdint.h>

// Problem: S=512, N=64, E=256, NH=8, HD=32, LH=512.
// Pipeline: convert -> qkv -> attn -> outproj -> gates GEMM -> persistent LSTM -> final proj.
// R18 = R17 with the k_lstm poll REVERTED to R16's serial single-replica walk.
// R17 lesson: the serial replica walk is a CLOCK — each fresh-address read is one
// RTT-spaced sample; pair-reading consumes 2 replicas per sample, halving the coverage
// window -> more IC-fallback spills (787 -> 854us). Restored verbatim.
// Kept: R16 slot-major h-ring (the -42% win: full-line producer writes, 8x fewer
// consumer read lines), bf16 weight pre-convert for k_qkv/k_outproj staging,
// m97-staged k_gates, 1024-block k_attn with vectorized softmax + P-writeback.

typedef __attribute__((ext_vector_type(8))) short bf16x8;
typedef __attribute__((ext_vector_type(4))) float f32x4;

__device__ __forceinline__ unsigned short f2bf(float f){
  unsigned u = __float_as_uint(f);
  u += 0x7FFFu + ((u >> 16) & 1u);          // RNE
  return (unsigned short)(u >> 16);
}
__device__ __forceinline__ float b2f(unsigned short h){
  return __uint_as_float(((unsigned)h) << 16);
}
__device__ __forceinline__ ushort4 f4tobf(float4 f){
  ushort4 o; o.x=f2bf(f.x); o.y=f2bf(f.y); o.z=f2bf(f.z); o.w=f2bf(f.w); return o;
}
// async global->LDS, 16B per lane: per-lane global src, wave-uniform LDS base (+lane*16).
__device__ __forceinline__ void gload_lds16(const void* g, void* l){
  __builtin_amdgcn_global_load_lds((const __attribute__((address_space(1))) unsigned int*)g,
                                   (__attribute__((address_space(3))) unsigned int*)l, 16, 0, 0);
}

// ---------------- workspace layout (bytes) ----------------
// flagsIC:  [0x0,      0x4000)   8 groups x 32 slots, 64B stride (IC fallback flags)
// cnt:      [0x4000,   0x4020)   8 ints, per-XCD slot claim
// pooled:   [0x30000,  0x50000)  64x512 f32
// w_ih bf16:[0x50000,  0x250000)
// in_w bf16:[0x250000, 0x2B0000) 768x256
// mo_w bf16:[0x2B0000, 0x2D0000) 256x256
// flr:      [0x300000, 0x700000) replicated L2 flags: [st][r<8][g][slot] int, 4MB
// combined: [0x800000, 0x2800000) 32768x512 bf16; REUSED by k_lstm as h-ring:
//           ring[st][g][slot][batch][u16] = 8KB per (st,g); 64KB/step, 32MB total
// gates:    [0x3000000,0xB000000) layout [m][u][gate] = m*2048 + u*4 + gate (aliases q/k/v/ctx)
// q:0x3000000 k:0x4000000 v:0x5000000 ctx:0x6000000 (each 16MB bf16)
// total required ws: 0xB000000 = 184,549,376 B

// K0: w_ih, x, in_proj_w, mha_out_w  fp32 -> bf16
__global__ __launch_bounds__(256) void k_convert(const float* __restrict__ wih,
                                                 const float* __restrict__ x,
                                                 const float* __restrict__ inw,
                                                 const float* __restrict__ mow,
                                                 unsigned short* __restrict__ wih_bf,
                                                 unsigned short* __restrict__ comb,
                                                 unsigned short* __restrict__ inw_bf,
                                                 unsigned short* __restrict__ mow_bf){
  size_t i = ((size_t)blockIdx.x * 256 + threadIdx.x) * 4;
  if (i < 1048576){
    float4 f = *(const float4*)(wih + i);
    *(ushort4*)(wih_bf + i) = f4tobf(f);
  } else {
    size_t j = i - 1048576;
    if (j < 8388608){
      float4 f = *(const float4*)(x + j);
      size_t m = j >> 8, c = j & 255;
      *(ushort4*)(comb + m*512 + c) = f4tobf(f);
    } else {
      size_t p = j - 8388608;
      if (p < 196608){
        float4 f = *(const float4*)(inw + p);
        *(ushort4*)(inw_bf + p) = f4tobf(f);
      } else {
        size_t qq = p - 196608;
        if (qq < 65536){
          float4 f = *(const float4*)(mow + qq);
          *(ushort4*)(mow_bf + qq) = f4tobf(f);
        }
      }
    }
  }
}

// K1: qkv = x @ in_proj_w.T + b ; scale folded into q; writes q/k [n][h][s][d], v transposed [n][h][d][s]
__global__ __launch_bounds__(256) void k_qkv(const unsigned short* __restrict__ xb,
                                             const unsigned short* __restrict__ wbf,
                                             const float* __restrict__ bias,
                                             unsigned short* __restrict__ q,
                                             unsigned short* __restrict__ kk,
                                             unsigned short* __restrict__ v){
  const int nt = blockIdx.x;    // 0..11
  const int mt = blockIdx.y;    // 0..511  (= s, since M-row = s*64+n)
  __shared__ unsigned short Bs[64][264];
  const int t = threadIdx.x;
  { // stage B tile (bf16, pre-converted)
    int row = t >> 2, c0 = (t & 3) * 64;
    const unsigned short* src = wbf + (size_t)(nt*64 + row)*256 + c0;
    #pragma unroll
    for (int i = 0; i < 64; i += 8)
      *(bf16x8*)&Bs[row][c0 + i] = *(const bf16x8*)(src + i);
  }
  __syncthreads();
  const int w4 = t >> 6, l = t & 63, lr = l & 15, lc = l >> 4;
  f32x4 acc[4];
  #pragma unroll
  for (int i = 0; i < 4; ++i) acc[i] = (f32x4){0.f,0.f,0.f,0.f};
  const size_t arow = (size_t)(mt*64 + w4*16 + lr) * 512;  // A from combined (bf16 x)
  #pragma unroll
  for (int kt = 0; kt < 8; ++kt){
    bf16x8 a = *(const bf16x8*)(xb + arow + kt*32 + lc*8);
    #pragma unroll
    for (int n4 = 0; n4 < 4; ++n4){
      bf16x8 b = *(const bf16x8*)&Bs[n4*16 + lr][kt*32 + lc*8];
      acc[n4] = __builtin_amdgcn_mfma_f32_16x16x32_bf16(a, b, acc[n4], 0, 0, 0);
    }
  }
  const int s = mt;
  #pragma unroll
  for (int n4 = 0; n4 < 4; ++n4){
    int ncol = nt*64 + n4*16 + lr;
    float bv = bias[ncol];
    int which = ncol >> 8, rem = ncol & 255, hh = rem >> 5, d = rem & 31;
    #pragma unroll
    for (int reg = 0; reg < 4; ++reg){
      int nb = w4*16 + lc*4 + reg;   // batch
      float val = acc[n4][reg] + bv;
      if (which == 0){
        val *= 0.17677669529663687f;  // 1/sqrt(32)
        q[((size_t)(nb*8 + hh)*512 + s)*32 + d] = f2bf(val);
      } else if (which == 1){
        kk[((size_t)(nb*8 + hh)*512 + s)*32 + d] = f2bf(val);
      } else {
        v[((size_t)(nb*8 + hh)*32 + d)*512 + s] = f2bf(val);
      }
    }
  }
}

// K2: attention; 2 blocks per (n,h), each does 8 Q-tiles -> 1024 blocks, 4/CU.
// Vectorized softmax; P written back into sc (bit-identical); PV reads P directly.
__global__ __launch_bounds__(256) void k_attn(const unsigned short* __restrict__ q,
                                              const unsigned short* __restrict__ k,
                                              const unsigned short* __restrict__ v,
                                              unsigned short* __restrict__ ctx){
  const int bid = blockIdx.x;
  const int nh = bid >> 1, qh = bid & 1;
  const int n = nh >> 3, h = nh & 7;
  __shared__ unsigned short sc[32][520];
  __shared__ float red[32][8];
  __shared__ float rowinv[32];
  const unsigned short* qb = q + (size_t)nh * 512 * 32;
  const unsigned short* kb = k + (size_t)nh * 512 * 32;
  const unsigned short* vb = v + (size_t)nh * 32 * 512;
  const int t = threadIdx.x, w4 = t >> 6, l = t & 63, lr = l & 15, lc = l >> 4;
  const int r = t >> 3, cc = t & 7;
  for (int qt = qh*8; qt < qh*8 + 8; ++qt){
    const int s0 = qt * 32;
    bf16x8 aq0 = *(const bf16x8*)(qb + (size_t)(s0 + lr)*32 + lc*8);
    bf16x8 aq1 = *(const bf16x8*)(qb + (size_t)(s0 + 16 + lr)*32 + lc*8);
    #pragma unroll
    for (int j = 0; j < 8; ++j){
      int ntl = w4*8 + j;
      bf16x8 bk = *(const bf16x8*)(kb + (size_t)(ntl*16 + lr)*32 + lc*8);
      f32x4 d0 = (f32x4){0.f,0.f,0.f,0.f}, d1 = (f32x4){0.f,0.f,0.f,0.f};
      d0 = __builtin_amdgcn_mfma_f32_16x16x32_bf16(aq0, bk, d0, 0, 0, 0);
      d1 = __builtin_amdgcn_mfma_f32_16x16x32_bf16(aq1, bk, d1, 0, 0, 0);
      #pragma unroll
      for (int reg = 0; reg < 4; ++reg){
        sc[lc*4 + reg][ntl*16 + lr]      = f2bf(d0[reg]);
        sc[16 + lc*4 + reg][ntl*16 + lr] = f2bf(d1[reg]);
      }
    }
    __syncthreads();
    float pm = -1e30f;
    #pragma unroll
    for (int i = 0; i < 8; ++i){
      bf16x8 vv = *(const bf16x8*)&sc[r][(i*8 + cc)*8];
      #pragma unroll
      for (int e = 0; e < 8; ++e) pm = fmaxf(pm, b2f((unsigned short)vv[e]));
    }
    red[r][cc] = pm;
    __syncthreads();
    float mfull = red[r][0];
    #pragma unroll
    for (int i = 1; i < 8; ++i) mfull = fmaxf(mfull, red[r][i]);
    __syncthreads();
    float sum = 0.f;
    #pragma unroll
    for (int i = 0; i < 8; ++i){
      bf16x8 vv = *(const bf16x8*)&sc[r][(i*8 + cc)*8];
      bf16x8 pv;
      #pragma unroll
      for (int e = 0; e < 8; ++e){
        float p = __expf(b2f((unsigned short)vv[e]) - mfull);
        sum += p;
        pv[e] = (short)f2bf(p);
      }
      *(bf16x8*)&sc[r][(i*8 + cc)*8] = pv;
    }
    red[r][cc] = sum;
    __syncthreads();
    float ss = 0.f;
    #pragma unroll
    for (int i = 0; i < 8; ++i) ss += red[r][i];
    rowinv[r] = 1.f / ss;
    __syncthreads();
    const int mt = w4 >> 1, ntd = w4 & 1;
    const int arow = mt*16 + lr;
    f32x4 o = (f32x4){0.f,0.f,0.f,0.f};
    for (int kt = 0; kt < 16; ++kt){
      bf16x8 ap = *(const bf16x8*)&sc[arow][kt*32 + lc*8];
      bf16x8 bv = *(const bf16x8*)(vb + (size_t)(ntd*16 + lr)*512 + kt*32 + lc*8);
      o = __builtin_amdgcn_mfma_f32_16x16x32_bf16(ap, bv, o, 0, 0, 0);
    }
    #pragma unroll
    for (int reg = 0; reg < 4; ++reg){
      int row = mt*16 + lc*4 + reg;
      int d = ntd*16 + lr;
      float val = o[reg] * rowinv[row];
      ctx[((size_t)(s0 + row)*64 + n)*256 + h*32 + d] = f2bf(val);
    }
    __syncthreads();
  }
}

// K3: attn_out = ctx @ mha_out_w.T + b -> combined[:, 256:512]
__global__ __launch_bounds__(256) void k_outproj(const unsigned short* __restrict__ ctx,
                                                 const unsigned short* __restrict__ wbf,
                                                 const float* __restrict__ bias,
                                                 unsigned short* __restrict__ comb){
  const int nt = blockIdx.x;   // 0..3
  const int mt = blockIdx.y;   // 0..511
  __shared__ unsigned short Bs[64][264];
  const int t = threadIdx.x;
  { // stage B tile (bf16, pre-converted)
    int row = t >> 2, c0 = (t & 3) * 64;
    const unsigned short* src = wbf + (size_t)(nt*64 + row)*256 + c0;
    #pragma unroll
    for (int i = 0; i < 64; i += 8)
      *(bf16x8*)&Bs[row][c0 + i] = *(const bf16x8*)(src + i);
  }
  __syncthreads();
  const int w4 = t >> 6, l = t & 63, lr = l & 15, lc = l >> 4;
  f32x4 acc[4];
  #pragma unroll
  for (int i = 0; i < 4; ++i) acc[i] = (f32x4){0.f,0.f,0.f,0.f};
  const size_t arow = (size_t)(mt*64 + w4*16 + lr) * 256;
  #pragma unroll
  for (int kt = 0; kt < 8; ++kt){
    bf16x8 a = *(const bf16x8*)(ctx + arow + kt*32 + lc*8);
    #pragma unroll
    for (int n4 = 0; n4 < 4; ++n4){
      bf16x8 b = *(const bf16x8*)&Bs[n4*16 + lr][kt*32 + lc*8];
      acc[n4] = __builtin_amdgcn_mfma_f32_16x16x32_bf16(a, b, acc[n4], 0, 0, 0);
    }
  }
  #pragma unroll
  for (int n4 = 0; n4 < 4; ++n4){
    int ncol = nt*64 + n4*16 + lr;
    float bv = bias[ncol];
    #pragma unroll
    for (int reg = 0; reg < 4; ++reg){
      int m = mt*64 + w4*16 + lc*4 + reg;
      comb[(size_t)m*512 + 256 + ncol] = f2bf(acc[n4][reg] + bv);
    }
  }
}

// K4: gates_x = combined @ w_ih.T + (b_ih + b_hh), 128x128 tiles, BK=64.
// m97-style staging: global_load_lds(16B) into linear [128][64] LDS; XOR chunk swizzle
// on GLOBAL source + LDS read. Output: gates[m][u][gate] = m*2048+u*4+gate.
__global__ __launch_bounds__(256) void k_gates(const unsigned short* __restrict__ A,
                                               const unsigned short* __restrict__ B,
                                               const float* __restrict__ bih,
                                               const float* __restrict__ bhh,
                                               unsigned short* __restrict__ gates){
  const int ntile = blockIdx.x;  // 0..15
  const int mtile = blockIdx.y;  // 0..255
  __shared__ unsigned short As[128][64], Bss[128][64];
  const int t = threadIdx.x, w4 = t >> 6, l = t & 63, lr = l & 15, lc = l >> 4;
  const int wm = w4 >> 1, wn = w4 & 1;
  f32x4 acc[4][4];
  #pragma unroll
  for (int i = 0; i < 4; ++i)
    #pragma unroll
    for (int j = 0; j < 4; ++j) acc[i][j] = (f32x4){0.f,0.f,0.f,0.f};
  const int ch = (l & 7) ^ (l >> 3);       // inverse-swizzled global chunk for this lane
  for (int kkk = 0; kkk < 8; ++kkk){
    #pragma unroll
    for (int c = 0; c < 4; ++c){
      const int row = w4*32 + c*8 + (l >> 3);
      gload_lds16(A + (size_t)(mtile*128 + row)*512 + kkk*64 + ch*8, &As [w4*32 + c*8][0]);
      gload_lds16(B + (size_t)(ntile*128 + row)*512 + kkk*64 + ch*8, &Bss[w4*32 + c*8][0]);
    }
    __syncthreads();   // compiler drains vmcnt before s_barrier -> LDS tiles complete
    #pragma unroll
    for (int kt = 0; kt < 2; ++kt){
      bf16x8 af[4], bfr[4];
      #pragma unroll
      for (int i = 0; i < 4; ++i)
        af[i]  = *(const bf16x8*)&As [wm*64 + i*16 + lr][(((kt*4 + lc) ^ (lr & 7)) * 8)];
      #pragma unroll
      for (int i = 0; i < 4; ++i)
        bfr[i] = *(const bf16x8*)&Bss[wn*64 + i*16 + lr][(((kt*4 + lc) ^ (lr & 7)) * 8)];
      #pragma unroll
      for (int i = 0; i < 4; ++i)
        #pragma unroll
        for (int j = 0; j < 4; ++j)
          acc[i][j] = __builtin_amdgcn_mfma_f32_16x16x32_bf16(af[i], bfr[j], acc[i][j], 0, 0, 0);
    }
    __syncthreads();
  }
  #pragma unroll
  for (int i = 0; i < 4; ++i){
    #pragma unroll
    for (int j = 0; j < 4; ++j){
      int ncol = ntile*128 + wn*64 + j*16 + lr;
      int gate = ncol >> 9, u = ncol & 511;
      float bsum = bih[ncol] + bhh[ncol];
      #pragma unroll
      for (int reg = 0; reg < 4; ++reg){
        int m = mtile*128 + wm*64 + i*16 + lc*4 + reg;
        gates[(size_t)m*2048 + u*4 + gate] = f2bf(acc[i][j][reg] + bsum);
      }
    }
  }
}

// K5: persistent LSTM, XCD-local — R16 VERBATIM (best measured: 787us).
// ring[st][g] = [slot][batch][u16]: producer waves write ONE contiguous 128B line;
// consumer loads 16x b128. Handshake: serial single-replica L2 walk + IC fallback.
__global__ __launch_bounds__(256, 1) void k_lstm(const float* __restrict__ whh,
                                                 const unsigned short* __restrict__ gates,
                                                 unsigned short* __restrict__ ring,
                                                 float* __restrict__ pooled,
                                                 int* __restrict__ flagsIC,
                                                 int* __restrict__ flr,
                                                 int* __restrict__ cnt){
  __shared__ unsigned short Wl[64][512];   // 64KB: rows = gate*16+unit
  __shared__ f32x4 Dg[4*2*16];             // 2KB:  [gate][lc][unit]
  __shared__ float padlds[5120];           // 20KB pad -> 86KB total -> 1 WG/CU
  __shared__ int s_hdr[2];
  const int t = threadIdx.x, w4 = t >> 6, l = t & 63, lr = l & 15, lc = l >> 4;
  if ((int)blockIdx.x == -1) ((volatile float*)padlds)[0] = 1.f;  // keep padlds
  if (t == 0){
    unsigned xcc;
    asm volatile("s_getreg_b32 %0, hwreg(HW_REG_XCC_ID)" : "=s"(xcc));
    int g = (int)(xcc & 7);
    s_hdr[0] = g;
    s_hdr[1] = atomicAdd(&cnt[g], 1);      // device-scope claim
  }
  __syncthreads();
  const int g = s_hdr[0], slot = s_hdr[1];
  if (slot >= 32) return;                  // spare WG: free the CU immediately
  const int j0 = slot * 16;
  { // stage w_hh slice fp32->bf16, chunk swizzle phys = logical ^ (row&7)
    const int row = t >> 2;
    const int gate = row >> 4, u = row & 15;
    const float* src = whh + (size_t)(gate*512 + j0 + u) * 512;
    const int cbase = (t & 3) * 16;
    #pragma unroll
    for (int i = 0; i < 16; ++i){
      const int lch = cbase + i;
      float4 f0 = *(const float4*)(src + lch*8);
      float4 f1 = *(const float4*)(src + lch*8 + 4);
      const int pch = lch ^ (row & 7);
      *(ushort4*)&Wl[row][pch*8]     = f4tobf(f0);
      *(ushort4*)&Wl[row][pch*8 + 4] = f4tobf(f1);
    }
  }
  const int eb = t >> 4, eu = t & 15;      // elementwise ownership, t<128: (batch, unit)
  float cst = 0.f, pool = 0.f;
  unsigned long long gx = 0, nx = 0;
  if (t < 128)
    gx = *(const unsigned long long*)(gates + (size_t)(g*8 + eb)*2048 + (j0 + eu)*4);
  int* const myflagIC = &flagsIC[(g*32 + slot)*16];
  __syncthreads();
  for (int st = 0; st < 512; ++st){
    if (st > 0){
      if (t < 32){
        // serial single-replica fresh-address walk (R16-proven pacing): retry r reads
        // replica r -> fresh L1 line -> served by the local XCD L2.
        bool need = true;
        #pragma unroll 1
        for (int r = 0; r < 8 && need; ++r){
          int v = ((volatile const int*)flr)[((st*8 + r)*8 + g)*32 + (t & 31)];
          need = (bool)__any(v == 0);
        }
        if (need){
          // pathological skew: proven IC atomic poll (bounded, correct-by-delay)
          int* fp = &flagsIC[(g*32 + (t & 31))*16];
          int t2 = 0;
          while (__hip_atomic_load(fp, __ATOMIC_RELAXED, __HIP_MEMORY_SCOPE_AGENT) < st
                 && ++t2 < 5000) { }
        }
      }
      __syncthreads();
    }
    // h(st) @ Wl^T : slot-major ring; element (b, u) at base + (u>>4)*128 + b*16 + (u&15).
    const unsigned short* ha = ring + (((size_t)st*8 + g) << 12)
                               + (lc >> 1)*128 + (lr & 7)*16 + (lc & 1)*8;
    bf16x8 areg[16];
    #pragma unroll
    for (int kt = 0; kt < 16; ++kt) areg[kt] = *(const bf16x8*)(ha + kt*256);
    if (st < 511 && t < 128)
      nx = *(const unsigned long long*)(gates + ((size_t)(st+1)*64 + g*8 + eb)*2048 + (j0 + eu)*4);
    f32x4 acc0 = (f32x4){0.f,0.f,0.f,0.f}, acc1 = (f32x4){0.f,0.f,0.f,0.f};
    #pragma unroll
    for (int kt = 0; kt < 16; kt += 2){
      bf16x8 b0 = *(const bf16x8*)&Wl[w4*16 + lr][(((kt  )*4 + lc) ^ (lr & 7)) * 8];
      bf16x8 b1 = *(const bf16x8*)&Wl[w4*16 + lr][(((kt+1)*4 + lc) ^ (lr & 7)) * 8];
      acc0 = __builtin_amdgcn_mfma_f32_16x16x32_bf16(areg[kt],   b0, acc0, 0, 0, 0);
      acc1 = __builtin_amdgcn_mfma_f32_16x16x32_bf16(areg[kt+1], b1, acc1, 0, 0, 0);
    }
    f32x4 acc = acc0 + acc1;
    if (lc < 2) Dg[(w4*2 + lc)*16 + lr] = acc;   // D: col=unit(lane&15), row=batch(lc*4+reg)
    __syncthreads();
    if (t < 128){
      union { unsigned long long q; unsigned short u[4]; } ga; ga.q = gx;
      const int dq = (eb >> 2)*16 + eu, dr = eb & 3;
      float gi = Dg[0*32 + dq][dr] + b2f(ga.u[0]);
      float gf = Dg[1*32 + dq][dr] + b2f(ga.u[1]);
      float gc = Dg[2*32 + dq][dr] + b2f(ga.u[2]);
      float go = Dg[3*32 + dq][dr] + b2f(ga.u[3]);
      float i_ = __builtin_amdgcn_rcpf(1.f + __expf(-gi));
      float f_ = __builtin_amdgcn_rcpf(1.f + __expf(-gf));
      float cg = fminf(fmaxf(gc, -20.f), 20.f);
      float e2 = __expf(2.f * cg);
      float g_ = 1.f - 2.f * __builtin_amdgcn_rcpf(e2 + 1.f);
      float o_ = __builtin_amdgcn_rcpf(1.f + __expf(-go));
      float cn = f_ * cst + i_ * g_;
      cst = cn;
      float ct = fminf(fmaxf(cn, -20.f), 20.f);
      float e2c = __expf(2.f * ct);
      float th = 1.f - 2.f * __builtin_amdgcn_rcpf(e2c + 1.f);
      float hh = o_ * th;
      pool += hh;
      if (st < 511)  // slot-major: lanes t<128 write offsets slot*128+t -> each wave
                     // one contiguous 128B line, write-through to this XCD's L2
        ring[(((size_t)(st+1)*8 + g) << 12) + slot*128 + t] = f2bf(hh);
      gx = nx;
    }
    __syncthreads();   // pre-barrier vmcnt(0) drains h stores to L2 [m97-measured semantics]
    if (st < 511){
      // h(st+1) in L2 now. Notify: 8 write-once L2 replicas (flag-in-L2 => h-in-L2,
      // same cache) + 1 IC flag for the fallback path.
      if (t < 8) flr[(((st+1)*8 + t)*8 + g)*32 + slot] = 1;
      if (t == 0) __hip_atomic_store(myflagIC, st + 1, __ATOMIC_RELAXED, __HIP_MEMORY_SCOPE_AGENT);
    }
  }
  if (t < 128)
    pooled[(size_t)(g*8 + eb)*512 + j0 + eu] = pool * (1.f / 512.f);
}

// K6: out = log_sigmoid(pooled @ proj_w.T + proj_b)
__global__ __launch_bounds__(256) void k_final(const float* __restrict__ pooled,
                                               const float* __restrict__ w,
                                               const float* __restrict__ bias,
                                               float* __restrict__ out){
  const int n = blockIdx.x;
  __shared__ float pr[512];
  const int t = threadIdx.x;
  pr[t]       = pooled[(size_t)n*512 + t];
  pr[t + 256] = pooled[(size_t)n*512 + t + 256];
  __syncthreads();
  const float* wr = w + (size_t)t * 512;
  float s = bias[t];
  for (int i = 0; i < 512; i += 4){
    float4 f = *(const float4*)(wr + i);
    s += f.x*pr[i] + f.y*pr[i+1] + f.z*pr[i+2] + f.w*pr[i+3];
  }
  float rres = fminf(s, 0.f) - log1pf(__expf(-fabsf(s)));
  out[(size_t)n*256 + t] = rres;
}

extern "C" void kernel_launch(void* const* d_in, const int* in_sizes, int n_in,
                              void* d_out, int out_size, void* d_ws, size_t ws_size,
                              hipStream_t stream){
  const float* x      = (const float*)d_in[0];
  const float* in_w   = (const float*)d_in[1];
  const float* in_b   = (const float*)d_in[2];
  const float* mo_w   = (const float*)d_in[3];
  const float* mo_b   = (const float*)d_in[4];
  const float* w_ih   = (const float*)d_in[5];
  const float* w_hh   = (const float*)d_in[6];
  const float* b_ih   = (const float*)d_in[7];
  const float* b_hh   = (const float*)d_in[8];
  const float* proj_w = (const float*)d_in[9];
  const float* proj_b = (const float*)d_in[10];
  uint8_t* ws = (uint8_t*)d_ws;
  int*            flagsIC = (int*)(ws + 0x0);
  int*            cnt     = (int*)(ws + 0x4000);
  float*          pooled  = (float*)(ws + 0x30000);
  unsigned short* wihbf   = (unsigned short*)(ws + 0x50000);
  unsigned short* inwbf   = (unsigned short*)(ws + 0x250000);
  unsigned short* mowbf   = (unsigned short*)(ws + 0x2B0000);
  int*            flr     = (int*)(ws + 0x300000);
  unsigned short* comb    = (unsigned short*)(ws + 0x800000);  // doubles as h-ring in k_lstm
  unsigned short* gates   = (unsigned short*)(ws + 0x3000000);
  unsigned short* qbuf    = (unsigned short*)(ws + 0x3000000); // aliases gates (dead before k_gates)
  unsigned short* kbuf    = (unsigned short*)(ws + 0x4000000);
  unsigned short* vbuf    = (unsigned short*)(ws + 0x5000000);
  unsigned short* ctx     = (unsigned short*)(ws + 0x6000000);

  hipMemsetAsync(ws + 0x300000, 0, 0x400000, stream);  // flr
  hipMemsetAsync(ws, 0, 0x4020, stream);               // flagsIC + cnt
  hipLaunchKernelGGL(k_convert, dim3(9472),    dim3(256), 0, stream, w_ih, x, in_w, mo_w,
                     wihbf, comb, inwbf, mowbf);
  hipLaunchKernelGGL(k_qkv,     dim3(12, 512), dim3(256), 0, stream, comb, inwbf, in_b, qbuf, kbuf, vbuf);
  hipLaunchKernelGGL(k_attn,    dim3(1024),    dim3(256), 0, stream, qbuf, kbuf, vbuf, ctx);
  hipLaunchKernelGGL(k_outproj, dim3(4, 512),  dim3(256), 0, stream, ctx, mowbf, mo_b, comb);
  hipLaunchKernelGGL(k_gates,   dim3(16, 256), dim3(256), 0, stream, comb, wihbf, b_ih, b_hh, gates);
  hipMemsetAsync(comb, 0, 0x10000, stream);  // h-ring slot 0 = h(-1) = zeros (comb dead now)
  hipLaunchKernelGGL(k_lstm,    dim3(512),     dim3(256), 0, stream, w_hh, gates, comb, pooled, flagsIC, flr, cnt);
  hipLaunchKernelGGL(k_final,   dim3(64),      dim3(256), 0, stream, pooled, proj_w, proj_b, (float*)d_out);
}

// Round 13
// 1114.400 us; speedup vs baseline: 1.1297x; 1.0097x over previous
//
#include <hip/hip_runtime.h>
#include <hip/hip_bf16.h>
#include <stdint.h>

// Problem: S=512, N=64, E=256, NH=8, HD=32, LH=512.
// Pipeline: convert -> qkv -> attn -> outproj -> gates GEMM -> persistent LSTM -> final proj.
// R19 = R18 (best: 1125us total, 719us k_lstm) + B-tile amortization in the tail:
//  - k_qkv: grid (12,256); each block stages its Bs ONCE and computes 2 consecutive
//    M-tiles (was 512 redundant stagings per column-strip). Bit-identical per-tile math.
//  - k_outproj: grid (4,256), same 2-Mtile amortization.
//  - k_lstm, k_gates, k_attn, k_convert, k_final: VERBATIM R18.

typedef __attribute__((ext_vector_type(8))) short bf16x8;
typedef __attribute__((ext_vector_type(4))) float f32x4;

__device__ __forceinline__ unsigned short f2bf(float f){
  unsigned u = __float_as_uint(f);
  u += 0x7FFFu + ((u >> 16) & 1u);          // RNE
  return (unsigned short)(u >> 16);
}
__device__ __forceinline__ float b2f(unsigned short h){
  return __uint_as_float(((unsigned)h) << 16);
}
__device__ __forceinline__ ushort4 f4tobf(float4 f){
  ushort4 o; o.x=f2bf(f.x); o.y=f2bf(f.y); o.z=f2bf(f.z); o.w=f2bf(f.w); return o;
}
// async global->LDS, 16B per lane: per-lane global src, wave-uniform LDS base (+lane*16).
__device__ __forceinline__ void gload_lds16(const void* g, void* l){
  __builtin_amdgcn_global_load_lds((const __attribute__((address_space(1))) unsigned int*)g,
                                   (__attribute__((address_space(3))) unsigned int*)l, 16, 0, 0);
}

// ---------------- workspace layout (bytes) ----------------
// flagsIC:  [0x0,      0x4000)   8 groups x 32 slots, 64B stride (IC fallback flags)
// cnt:      [0x4000,   0x4020)   8 ints, per-XCD slot claim
// pooled:   [0x30000,  0x50000)  64x512 f32
// w_ih bf16:[0x50000,  0x250000)
// in_w bf16:[0x250000, 0x2B0000) 768x256
// mo_w bf16:[0x2B0000, 0x2D0000) 256x256
// flr:      [0x300000, 0x700000) replicated L2 flags: [st][r<8][g][slot] int, 4MB
// combined: [0x800000, 0x2800000) 32768x512 bf16; REUSED by k_lstm as h-ring:
//           ring[st][g][slot][batch][u16] = 8KB per (st,g); 64KB/step, 32MB total
// gates:    [0x3000000,0xB000000) layout [m][u][gate] = m*2048 + u*4 + gate (aliases q/k/v/ctx)
// q:0x3000000 k:0x4000000 v:0x5000000 ctx:0x6000000 (each 16MB bf16)
// total required ws: 0xB000000 = 184,549,376 B

// K0: w_ih, x, in_proj_w, mha_out_w  fp32 -> bf16
__global__ __launch_bounds__(256) void k_convert(const float* __restrict__ wih,
                                                 const float* __restrict__ x,
                                                 const float* __restrict__ inw,
                                                 const float* __restrict__ mow,
                                                 unsigned short* __restrict__ wih_bf,
                                                 unsigned short* __restrict__ comb,
                                                 unsigned short* __restrict__ inw_bf,
                                                 unsigned short* __restrict__ mow_bf){
  size_t i = ((size_t)blockIdx.x * 256 + threadIdx.x) * 4;
  if (i < 1048576){
    float4 f = *(const float4*)(wih + i);
    *(ushort4*)(wih_bf + i) = f4tobf(f);
  } else {
    size_t j = i - 1048576;
    if (j < 8388608){
      float4 f = *(const float4*)(x + j);
      size_t m = j >> 8, c = j & 255;
      *(ushort4*)(comb + m*512 + c) = f4tobf(f);
    } else {
      size_t p = j - 8388608;
      if (p < 196608){
        float4 f = *(const float4*)(inw + p);
        *(ushort4*)(inw_bf + p) = f4tobf(f);
      } else {
        size_t qq = p - 196608;
        if (qq < 65536){
          float4 f = *(const float4*)(mow + qq);
          *(ushort4*)(mow_bf + qq) = f4tobf(f);
        }
      }
    }
  }
}

// K1: qkv = x @ in_proj_w.T + b ; scale folded into q; writes q/k [n][h][s][d], v transposed [n][h][d][s]
// R19: one Bs staging serves 2 consecutive M-tiles (grid y halved).
__global__ __launch_bounds__(256) void k_qkv(const unsigned short* __restrict__ xb,
                                             const unsigned short* __restrict__ wbf,
                                             const float* __restrict__ bias,
                                             unsigned short* __restrict__ q,
                                             unsigned short* __restrict__ kk,
                                             unsigned short* __restrict__ v){
  const int nt = blockIdx.x;    // 0..11
  __shared__ unsigned short Bs[64][264];
  const int t = threadIdx.x;
  { // stage B tile (bf16, pre-converted)
    int row = t >> 2, c0 = (t & 3) * 64;
    const unsigned short* src = wbf + (size_t)(nt*64 + row)*256 + c0;
    #pragma unroll
    for (int i = 0; i < 64; i += 8)
      *(bf16x8*)&Bs[row][c0 + i] = *(const bf16x8*)(src + i);
  }
  __syncthreads();
  const int w4 = t >> 6, l = t & 63, lr = l & 15, lc = l >> 4;
  #pragma unroll 1
  for (int mi = 0; mi < 2; ++mi){
    const int mt = blockIdx.y*2 + mi;   // 0..511 (= s)
    f32x4 acc[4];
    #pragma unroll
    for (int i = 0; i < 4; ++i) acc[i] = (f32x4){0.f,0.f,0.f,0.f};
    const size_t arow = (size_t)(mt*64 + w4*16 + lr) * 512;  // A from combined (bf16 x)
    #pragma unroll
    for (int kt = 0; kt < 8; ++kt){
      bf16x8 a = *(const bf16x8*)(xb + arow + kt*32 + lc*8);
      #pragma unroll
      for (int n4 = 0; n4 < 4; ++n4){
        bf16x8 b = *(const bf16x8*)&Bs[n4*16 + lr][kt*32 + lc*8];
        acc[n4] = __builtin_amdgcn_mfma_f32_16x16x32_bf16(a, b, acc[n4], 0, 0, 0);
      }
    }
    const int s = mt;
    #pragma unroll
    for (int n4 = 0; n4 < 4; ++n4){
      int ncol = nt*64 + n4*16 + lr;
      float bv = bias[ncol];
      int which = ncol >> 8, rem = ncol & 255, hh = rem >> 5, d = rem & 31;
      #pragma unroll
      for (int reg = 0; reg < 4; ++reg){
        int nb = w4*16 + lc*4 + reg;   // batch
        float val = acc[n4][reg] + bv;
        if (which == 0){
          val *= 0.17677669529663687f;  // 1/sqrt(32)
          q[((size_t)(nb*8 + hh)*512 + s)*32 + d] = f2bf(val);
        } else if (which == 1){
          kk[((size_t)(nb*8 + hh)*512 + s)*32 + d] = f2bf(val);
        } else {
          v[((size_t)(nb*8 + hh)*32 + d)*512 + s] = f2bf(val);
        }
      }
    }
  }
}

// K2: attention; 2 blocks per (n,h), each does 8 Q-tiles -> 1024 blocks, 4/CU.
// Vectorized softmax; P written back into sc (bit-identical); PV reads P directly.
__global__ __launch_bounds__(256) void k_attn(const unsigned short* __restrict__ q,
                                              const unsigned short* __restrict__ k,
                                              const unsigned short* __restrict__ v,
                                              unsigned short* __restrict__ ctx){
  const int bid = blockIdx.x;
  const int nh = bid >> 1, qh = bid & 1;
  const int n = nh >> 3, h = nh & 7;
  __shared__ unsigned short sc[32][520];
  __shared__ float red[32][8];
  __shared__ float rowinv[32];
  const unsigned short* qb = q + (size_t)nh * 512 * 32;
  const unsigned short* kb = k + (size_t)nh * 512 * 32;
  const unsigned short* vb = v + (size_t)nh * 32 * 512;
  const int t = threadIdx.x, w4 = t >> 6, l = t & 63, lr = l & 15, lc = l >> 4;
  const int r = t >> 3, cc = t & 7;
  for (int qt = qh*8; qt < qh*8 + 8; ++qt){
    const int s0 = qt * 32;
    bf16x8 aq0 = *(const bf16x8*)(qb + (size_t)(s0 + lr)*32 + lc*8);
    bf16x8 aq1 = *(const bf16x8*)(qb + (size_t)(s0 + 16 + lr)*32 + lc*8);
    #pragma unroll
    for (int j = 0; j < 8; ++j){
      int ntl = w4*8 + j;
      bf16x8 bk = *(const bf16x8*)(kb + (size_t)(ntl*16 + lr)*32 + lc*8);
      f32x4 d0 = (f32x4){0.f,0.f,0.f,0.f}, d1 = (f32x4){0.f,0.f,0.f,0.f};
      d0 = __builtin_amdgcn_mfma_f32_16x16x32_bf16(aq0, bk, d0, 0, 0, 0);
      d1 = __builtin_amdgcn_mfma_f32_16x16x32_bf16(aq1, bk, d1, 0, 0, 0);
      #pragma unroll
      for (int reg = 0; reg < 4; ++reg){
        sc[lc*4 + reg][ntl*16 + lr]      = f2bf(d0[reg]);
        sc[16 + lc*4 + reg][ntl*16 + lr] = f2bf(d1[reg]);
      }
    }
    __syncthreads();
    float pm = -1e30f;
    #pragma unroll
    for (int i = 0; i < 8; ++i){
      bf16x8 vv = *(const bf16x8*)&sc[r][(i*8 + cc)*8];
      #pragma unroll
      for (int e = 0; e < 8; ++e) pm = fmaxf(pm, b2f((unsigned short)vv[e]));
    }
    red[r][cc] = pm;
    __syncthreads();
    float mfull = red[r][0];
    #pragma unroll
    for (int i = 1; i < 8; ++i) mfull = fmaxf(mfull, red[r][i]);
    __syncthreads();
    float sum = 0.f;
    #pragma unroll
    for (int i = 0; i < 8; ++i){
      bf16x8 vv = *(const bf16x8*)&sc[r][(i*8 + cc)*8];
      bf16x8 pv;
      #pragma unroll
      for (int e = 0; e < 8; ++e){
        float p = __expf(b2f((unsigned short)vv[e]) - mfull);
        sum += p;
        pv[e] = (short)f2bf(p);
      }
      *(bf16x8*)&sc[r][(i*8 + cc)*8] = pv;
    }
    red[r][cc] = sum;
    __syncthreads();
    float ss = 0.f;
    #pragma unroll
    for (int i = 0; i < 8; ++i) ss += red[r][i];
    rowinv[r] = 1.f / ss;
    __syncthreads();
    const int mt = w4 >> 1, ntd = w4 & 1;
    const int arow = mt*16 + lr;
    f32x4 o = (f32x4){0.f,0.f,0.f,0.f};
    for (int kt = 0; kt < 16; ++kt){
      bf16x8 ap = *(const bf16x8*)&sc[arow][kt*32 + lc*8];
      bf16x8 bv = *(const bf16x8*)(vb + (size_t)(ntd*16 + lr)*512 + kt*32 + lc*8);
      o = __builtin_amdgcn_mfma_f32_16x16x32_bf16(ap, bv, o, 0, 0, 0);
    }
    #pragma unroll
    for (int reg = 0; reg < 4; ++reg){
      int row = mt*16 + lc*4 + reg;
      int d = ntd*16 + lr;
      float val = o[reg] * rowinv[row];
      ctx[((size_t)(s0 + row)*64 + n)*256 + h*32 + d] = f2bf(val);
    }
    __syncthreads();
  }
}

// K3: attn_out = ctx @ mha_out_w.T + b -> combined[:, 256:512]
// R19: one Bs staging serves 2 consecutive M-tiles (grid y halved).
__global__ __launch_bounds__(256) void k_outproj(const unsigned short* __restrict__ ctx,
                                                 const unsigned short* __restrict__ wbf,
                                                 const float* __restrict__ bias,
                                                 unsigned short* __restrict__ comb){
  const int nt = blockIdx.x;   // 0..3
  __shared__ unsigned short Bs[64][264];
  const int t = threadIdx.x;
  { // stage B tile (bf16, pre-converted)
    int row = t >> 2, c0 = (t & 3) * 64;
    const unsigned short* src = wbf + (size_t)(nt*64 + row)*256 + c0;
    #pragma unroll
    for (int i = 0; i < 64; i += 8)
      *(bf16x8*)&Bs[row][c0 + i] = *(const bf16x8*)(src + i);
  }
  __syncthreads();
  const int w4 = t >> 6, l = t & 63, lr = l & 15, lc = l >> 4;
  #pragma unroll 1
  for (int mi = 0; mi < 2; ++mi){
    const int mt = blockIdx.y*2 + mi;   // 0..511
    f32x4 acc[4];
    #pragma unroll
    for (int i = 0; i < 4; ++i) acc[i] = (f32x4){0.f,0.f,0.f,0.f};
    const size_t arow = (size_t)(mt*64 + w4*16 + lr) * 256;
    #pragma unroll
    for (int kt = 0; kt < 8; ++kt){
      bf16x8 a = *(const bf16x8*)(ctx + arow + kt*32 + lc*8);
      #pragma unroll
      for (int n4 = 0; n4 < 4; ++n4){
        bf16x8 b = *(const bf16x8*)&Bs[n4*16 + lr][kt*32 + lc*8];
        acc[n4] = __builtin_amdgcn_mfma_f32_16x16x32_bf16(a, b, acc[n4], 0, 0, 0);
      }
    }
    #pragma unroll
    for (int n4 = 0; n4 < 4; ++n4){
      int ncol = nt*64 + n4*16 + lr;
      float bv = bias[ncol];
      #pragma unroll
      for (int reg = 0; reg < 4; ++reg){
        int m = mt*64 + w4*16 + lc*4 + reg;
        comb[(size_t)m*512 + 256 + ncol] = f2bf(acc[n4][reg] + bv);
      }
    }
  }
}

// K4: gates_x = combined @ w_ih.T + (b_ih + b_hh), 128x128 tiles, BK=64.
// m97-style staging: global_load_lds(16B) into linear [128][64] LDS; XOR chunk swizzle
// on GLOBAL source + LDS read. Output: gates[m][u][gate] = m*2048+u*4+gate.
__global__ __launch_bounds__(256) void k_gates(const unsigned short* __restrict__ A,
                                               const unsigned short* __restrict__ B,
                                               const float* __restrict__ bih,
                                               const float* __restrict__ bhh,
                                               unsigned short* __restrict__ gates){
  const int ntile = blockIdx.x;  // 0..15
  const int mtile = blockIdx.y;  // 0..255
  __shared__ unsigned short As[128][64], Bss[128][64];
  const int t = threadIdx.x, w4 = t >> 6, l = t & 63, lr = l & 15, lc = l >> 4;
  const int wm = w4 >> 1, wn = w4 & 1;
  f32x4 acc[4][4];
  #pragma unroll
  for (int i = 0; i < 4; ++i)
    #pragma unroll
    for (int j = 0; j < 4; ++j) acc[i][j] = (f32x4){0.f,0.f,0.f,0.f};
  const int ch = (l & 7) ^ (l >> 3);       // inverse-swizzled global chunk for this lane
  for (int kkk = 0; kkk < 8; ++kkk){
    #pragma unroll
    for (int c = 0; c < 4; ++c){
      const int row = w4*32 + c*8 + (l >> 3);
      gload_lds16(A + (size_t)(mtile*128 + row)*512 + kkk*64 + ch*8, &As [w4*32 + c*8][0]);
      gload_lds16(B + (size_t)(ntile*128 + row)*512 + kkk*64 + ch*8, &Bss[w4*32 + c*8][0]);
    }
    __syncthreads();   // compiler drains vmcnt before s_barrier -> LDS tiles complete
    #pragma unroll
    for (int kt = 0; kt < 2; ++kt){
      bf16x8 af[4], bfr[4];
      #pragma unroll
      for (int i = 0; i < 4; ++i)
        af[i]  = *(const bf16x8*)&As [wm*64 + i*16 + lr][(((kt*4 + lc) ^ (lr & 7)) * 8)];
      #pragma unroll
      for (int i = 0; i < 4; ++i)
        bfr[i] = *(const bf16x8*)&Bss[wn*64 + i*16 + lr][(((kt*4 + lc) ^ (lr & 7)) * 8)];
      #pragma unroll
      for (int i = 0; i < 4; ++i)
        #pragma unroll
        for (int j = 0; j < 4; ++j)
          acc[i][j] = __builtin_amdgcn_mfma_f32_16x16x32_bf16(af[i], bfr[j], acc[i][j], 0, 0, 0);
    }
    __syncthreads();
  }
  #pragma unroll
  for (int i = 0; i < 4; ++i){
    #pragma unroll
    for (int j = 0; j < 4; ++j){
      int ncol = ntile*128 + wn*64 + j*16 + lr;
      int gate = ncol >> 9, u = ncol & 511;
      float bsum = bih[ncol] + bhh[ncol];
      #pragma unroll
      for (int reg = 0; reg < 4; ++reg){
        int m = mtile*128 + wm*64 + i*16 + lc*4 + reg;
        gates[(size_t)m*2048 + u*4 + gate] = f2bf(acc[i][j][reg] + bsum);
      }
    }
  }
}

// K5: persistent LSTM, XCD-local — R16/R18 VERBATIM (best measured: 719us).
// ring[st][g] = [slot][batch][u16]: producer waves write ONE contiguous 128B line;
// consumer loads 16x b128. Handshake: serial single-replica L2 walk + IC fallback.
__global__ __launch_bounds__(256, 1) void k_lstm(const float* __restrict__ whh,
                                                 const unsigned short* __restrict__ gates,
                                                 unsigned short* __restrict__ ring,
                                                 float* __restrict__ pooled,
                                                 int* __restrict__ flagsIC,
                                                 int* __restrict__ flr,
                                                 int* __restrict__ cnt){
  __shared__ unsigned short Wl[64][512];   // 64KB: rows = gate*16+unit
  __shared__ f32x4 Dg[4*2*16];             // 2KB:  [gate][lc][unit]
  __shared__ float padlds[5120];           // 20KB pad -> 86KB total -> 1 WG/CU
  __shared__ int s_hdr[2];
  const int t = threadIdx.x, w4 = t >> 6, l = t & 63, lr = l & 15, lc = l >> 4;
  if ((int)blockIdx.x == -1) ((volatile float*)padlds)[0] = 1.f;  // keep padlds
  if (t == 0){
    unsigned xcc;
    asm volatile("s_getreg_b32 %0, hwreg(HW_REG_XCC_ID)" : "=s"(xcc));
    int g = (int)(xcc & 7);
    s_hdr[0] = g;
    s_hdr[1] = atomicAdd(&cnt[g], 1);      // device-scope claim
  }
  __syncthreads();
  const int g = s_hdr[0], slot = s_hdr[1];
  if (slot >= 32) return;                  // spare WG: free the CU immediately
  const int j0 = slot * 16;
  { // stage w_hh slice fp32->bf16, chunk swizzle phys = logical ^ (row&7)
    const int row = t >> 2;
    const int gate = row >> 4, u = row & 15;
    const float* src = whh + (size_t)(gate*512 + j0 + u) * 512;
    const int cbase = (t & 3) * 16;
    #pragma unroll
    for (int i = 0; i < 16; ++i){
      const int lch = cbase + i;
      float4 f0 = *(const float4*)(src + lch*8);
      float4 f1 = *(const float4*)(src + lch*8 + 4);
      const int pch = lch ^ (row & 7);
      *(ushort4*)&Wl[row][pch*8]     = f4tobf(f0);
      *(ushort4*)&Wl[row][pch*8 + 4] = f4tobf(f1);
    }
  }
  const int eb = t >> 4, eu = t & 15;      // elementwise ownership, t<128: (batch, unit)
  float cst = 0.f, pool = 0.f;
  unsigned long long gx = 0, nx = 0;
  if (t < 128)
    gx = *(const unsigned long long*)(gates + (size_t)(g*8 + eb)*2048 + (j0 + eu)*4);
  int* const myflagIC = &flagsIC[(g*32 + slot)*16];
  __syncthreads();
  for (int st = 0; st < 512; ++st){
    if (st > 0){
      if (t < 32){
        // serial single-replica fresh-address walk (R16-proven pacing): retry r reads
        // replica r -> fresh L1 line -> served by the local XCD L2.
        bool need = true;
        #pragma unroll 1
        for (int r = 0; r < 8 && need; ++r){
          int v = ((volatile const int*)flr)[((st*8 + r)*8 + g)*32 + (t & 31)];
          need = (bool)__any(v == 0);
        }
        if (need){
          // pathological skew: proven IC atomic poll (bounded, correct-by-delay)
          int* fp = &flagsIC[(g*32 + (t & 31))*16];
          int t2 = 0;
          while (__hip_atomic_load(fp, __ATOMIC_RELAXED, __HIP_MEMORY_SCOPE_AGENT) < st
                 && ++t2 < 5000) { }
        }
      }
      __syncthreads();
    }
    // h(st) @ Wl^T : slot-major ring; element (b, u) at base + (u>>4)*128 + b*16 + (u&15).
    const unsigned short* ha = ring + (((size_t)st*8 + g) << 12)
                               + (lc >> 1)*128 + (lr & 7)*16 + (lc & 1)*8;
    bf16x8 areg[16];
    #pragma unroll
    for (int kt = 0; kt < 16; ++kt) areg[kt] = *(const bf16x8*)(ha + kt*256);
    if (st < 511 && t < 128)
      nx = *(const unsigned long long*)(gates + ((size_t)(st+1)*64 + g*8 + eb)*2048 + (j0 + eu)*4);
    f32x4 acc0 = (f32x4){0.f,0.f,0.f,0.f}, acc1 = (f32x4){0.f,0.f,0.f,0.f};
    #pragma unroll
    for (int kt = 0; kt < 16; kt += 2){
      bf16x8 b0 = *(const bf16x8*)&Wl[w4*16 + lr][(((kt  )*4 + lc) ^ (lr & 7)) * 8];
      bf16x8 b1 = *(const bf16x8*)&Wl[w4*16 + lr][(((kt+1)*4 + lc) ^ (lr & 7)) * 8];
      acc0 = __builtin_amdgcn_mfma_f32_16x16x32_bf16(areg[kt],   b0, acc0, 0, 0, 0);
      acc1 = __builtin_amdgcn_mfma_f32_16x16x32_bf16(areg[kt+1], b1, acc1, 0, 0, 0);
    }
    f32x4 acc = acc0 + acc1;
    if (lc < 2) Dg[(w4*2 + lc)*16 + lr] = acc;   // D: col=unit(lane&15), row=batch(lc*4+reg)
    __syncthreads();
    if (t < 128){
      union { unsigned long long q; unsigned short u[4]; } ga; ga.q = gx;
      const int dq = (eb >> 2)*16 + eu, dr = eb & 3;
      float gi = Dg[0*32 + dq][dr] + b2f(ga.u[0]);
      float gf = Dg[1*32 + dq][dr] + b2f(ga.u[1]);
      float gc = Dg[2*32 + dq][dr] + b2f(ga.u[2]);
      float go = Dg[3*32 + dq][dr] + b2f(ga.u[3]);
      float i_ = __builtin_amdgcn_rcpf(1.f + __expf(-gi));
      float f_ = __builtin_amdgcn_rcpf(1.f + __expf(-gf));
      float cg = fminf(fmaxf(gc, -20.f), 20.f);
      float e2 = __expf(2.f * cg);
      float g_ = 1.f - 2.f * __builtin_amdgcn_rcpf(e2 + 1.f);
      float o_ = __builtin_amdgcn_rcpf(1.f + __expf(-go));
      float cn = f_ * cst + i_ * g_;
      cst = cn;
      float ct = fminf(fmaxf(cn, -20.f), 20.f);
      float e2c = __expf(2.f * ct);
      float th = 1.f - 2.f * __builtin_amdgcn_rcpf(e2c + 1.f);
      float hh = o_ * th;
      pool += hh;
      if (st < 511)  // slot-major: lanes t<128 write offsets slot*128+t -> each wave
                     // one contiguous 128B line, write-through to this XCD's L2
        ring[(((size_t)(st+1)*8 + g) << 12) + slot*128 + t] = f2bf(hh);
      gx = nx;
    }
    __syncthreads();   // pre-barrier vmcnt(0) drains h stores to L2 [m97-measured semantics]
    if (st < 511){
      // h(st+1) in L2 now. Notify: 8 write-once L2 replicas (flag-in-L2 => h-in-L2,
      // same cache) + 1 IC flag for the fallback path.
      if (t < 8) flr[(((st+1)*8 + t)*8 + g)*32 + slot] = 1;
      if (t == 0) __hip_atomic_store(myflagIC, st + 1, __ATOMIC_RELAXED, __HIP_MEMORY_SCOPE_AGENT);
    }
  }
  if (t < 128)
    pooled[(size_t)(g*8 + eb)*512 + j0 + eu] = pool * (1.f / 512.f);
}

// K6: out = log_sigmoid(pooled @ proj_w.T + proj_b)
__global__ __launch_bounds__(256) void k_final(const float* __restrict__ pooled,
                                               const float* __restrict__ w,
                                               const float* __restrict__ bias,
                                               float* __restrict__ out){
  const int n = blockIdx.x;
  __shared__ float pr[512];
  const int t = threadIdx.x;
  pr[t]       = pooled[(size_t)n*512 + t];
  pr[t + 256] = pooled[(size_t)n*512 + t + 256];
  __syncthreads();
  const float* wr = w + (size_t)t * 512;
  float s = bias[t];
  for (int i = 0; i < 512; i += 4){
    float4 f = *(const float4*)(wr + i);
    s += f.x*pr[i] + f.y*pr[i+1] + f.z*pr[i+2] + f.w*pr[i+3];
  }
  float rres = fminf(s, 0.f) - log1pf(__expf(-fabsf(s)));
  out[(size_t)n*256 + t] = rres;
}

extern "C" void kernel_launch(void* const* d_in, const int* in_sizes, int n_in,
                              void* d_out, int out_size, void* d_ws, size_t ws_size,
                              hipStream_t stream){
  const float* x      = (const float*)d_in[0];
  const float* in_w   = (const float*)d_in[1];
  const float* in_b   = (const float*)d_in[2];
  const float* mo_w   = (const float*)d_in[3];
  const float* mo_b   = (const float*)d_in[4];
  const float* w_ih   = (const float*)d_in[5];
  const float* w_hh   = (const float*)d_in[6];
  const float* b_ih   = (const float*)d_in[7];
  const float* b_hh   = (const float*)d_in[8];
  const float* proj_w = (const float*)d_in[9];
  const float* proj_b = (const float*)d_in[10];
  uint8_t* ws = (uint8_t*)d_ws;
  int*            flagsIC = (int*)(ws + 0x0);
  int*            cnt     = (int*)(ws + 0x4000);
  float*          pooled  = (float*)(ws + 0x30000);
  unsigned short* wihbf   = (unsigned short*)(ws + 0x50000);
  unsigned short* inwbf   = (unsigned short*)(ws + 0x250000);
  unsigned short* mowbf   = (unsigned short*)(ws + 0x2B0000);
  int*            flr     = (int*)(ws + 0x300000);
  unsigned short* comb    = (unsigned short*)(ws + 0x800000);  // doubles as h-ring in k_lstm
  unsigned short* gates   = (unsigned short*)(ws + 0x3000000);
  unsigned short* qbuf    = (unsigned short*)(ws + 0x3000000); // aliases gates (dead before k_gates)
  unsigned short* kbuf    = (unsigned short*)(ws + 0x4000000);
  unsigned short* vbuf    = (unsigned short*)(ws + 0x5000000);
  unsigned short* ctx     = (unsigned short*)(ws + 0x6000000);

  hipMemsetAsync(ws + 0x300000, 0, 0x400000, stream);  // flr
  hipMemsetAsync(ws, 0, 0x4020, stream);               // flagsIC + cnt
  hipLaunchKernelGGL(k_convert, dim3(9472),    dim3(256), 0, stream, w_ih, x, in_w, mo_w,
                     wihbf, comb, inwbf, mowbf);
  hipLaunchKernelGGL(k_qkv,     dim3(12, 256), dim3(256), 0, stream, comb, inwbf, in_b, qbuf, kbuf, vbuf);
  hipLaunchKernelGGL(k_attn,    dim3(1024),    dim3(256), 0, stream, qbuf, kbuf, vbuf, ctx);
  hipLaunchKernelGGL(k_outproj, dim3(4, 256),  dim3(256), 0, stream, ctx, mowbf, mo_b, comb);
  hipLaunchKernelGGL(k_gates,   dim3(16, 256), dim3(256), 0, stream, comb, wihbf, b_ih, b_hh, gates);
  hipMemsetAsync(comb, 0, 0x10000, stream);  // h-ring slot 0 = h(-1) = zeros (comb dead now)
  hipLaunchKernelGGL(k_lstm,    dim3(512),     dim3(256), 0, stream, w_hh, gates, comb, pooled, flagsIC, flr, cnt);
  hipLaunchKernelGGL(k_final,   dim3(64),      dim3(256), 0, stream, pooled, proj_w, proj_b, (float*)d_out);
}